// Round 1
// baseline (1083.123 us; speedup 1.0000x reference)
//
#include <hip/hip_runtime.h>
#include <hip/hip_bf16.h>

#define BB   16
#define CC   64
#define SS   64
#define HWHW 1024
#define CD   32
#define QELEMS (BB * CD * SS * HWHW) /* 33554432 elems per q/k/v tensor */

typedef unsigned short ushort_t;
typedef __attribute__((ext_vector_type(8)))  short bf16x8;
typedef __attribute__((ext_vector_type(16))) float f32x16;

static __device__ inline float bf2f(ushort_t u) {
    union { float f; unsigned int i; } v;
    v.i = ((unsigned int)u) << 16;
    return v.f;
}
static __device__ inline ushort_t f2bf(float f) {
    union { float f; unsigned int i; } v;
    v.f = f;
    unsigned int x = v.i;
    return (ushort_t)((x + 0x7fffu + ((x >> 16) & 1u)) >> 16);
}

// ---------------------------------------------------------------------------
// Pack weights: Wt[tap][oc(96: q|k|v)][c(64)] bf16 and Wt2[tap][oc(64)][c(32)]
// so MFMA A-fragments (8 consecutive c) are single 16B loads.
// ---------------------------------------------------------------------------
__global__ __launch_bounds__(256) void pack_weights(
    const float* __restrict__ wq, const float* __restrict__ wk,
    const float* __restrict__ wv, const float* __restrict__ wo,
    ushort_t* __restrict__ wt, ushort_t* __restrict__ wt2)
{
    const int d = blockIdx.x * 256 + threadIdx.x;
    if (d < 9 * 96 * 64) {
        const int tap = d / (96 * 64);
        const int rem = d % (96 * 64);
        const int oc  = rem >> 6;
        const int c   = rem & 63;
        const float* wsrc = (oc < 32) ? wq : (oc < 64) ? wk : wv;
        const int ocl = oc & 31;
        wt[d] = f2bf(wsrc[((size_t)ocl * 64 + c) * 9 + tap]);
    }
    const int d2 = d - 9 * 96 * 64;
    if (d2 >= 0 && d2 < 9 * 64 * 32) {
        const int tap = d2 / (64 * 32);
        const int rem = d2 % (64 * 32);
        const int oc  = rem >> 5;
        const int c   = rem & 31;
        wt2[d2] = f2bf(wo[((size_t)oc * 32 + c) * 9 + tap]);
    }
}

// ---------------------------------------------------------------------------
// Kernel 1: fused q/k/v conv via implicit-GEMM MFMA.
// Block: one (b, s, 8-row pixel chunk). M=96 (q|k|v x32ch), N=256 px, K=64x9.
// LDS x tile: pixel-major [row 10][col 34][c 72pad] bf16, halo zero-padded.
// ---------------------------------------------------------------------------
__global__ __launch_bounds__(256) void conv_qkv_mfma(
    const float* __restrict__ x,
    const ushort_t* __restrict__ wt,
    const float* __restrict__ bq, const float* __restrict__ bk,
    const float* __restrict__ bv,
    ushort_t* __restrict__ qkv)
{
    __shared__ ushort_t xs[10][34][72];   // 48960 B

    const int tid   = threadIdx.x;
    const int bs    = blockIdx.x >> 2;
    const int chunk = blockIdx.x & 3;
    const int b     = bs >> 6;
    const int s     = bs & 63;
    const int h0    = chunk * 8;

    // zero the halo columns (col 0 and 33), c in [0,64)
    if (tid < 160) {
        const int r    = tid >> 4;
        const int rest = tid & 15;
        const int col  = (rest >> 3) ? 33 : 0;
        const int c0   = (rest & 7) << 3;
        bf16x8 z = {0, 0, 0, 0, 0, 0, 0, 0};
        *(bf16x8*)&xs[r][col][c0] = z;
    }

    // stage x rows h0-1 .. h0+8 (zeros outside image), fp32 -> bf16 transpose
    const float* xb = x + ((size_t)b * CC * SS + s) * HWHW;
#pragma unroll
    for (int it = 0; it < 20; ++it) {
        const int u  = tid + it * 256;      // 0..5119 = 64c * 10r * 8grp
        const int g  = u & 7;
        const int t2 = u >> 3;              // 0..639
        const int r  = t2 % 10;
        const int c  = t2 / 10;
        const int h  = h0 - 1 + r;
        float4 xv = make_float4(0.f, 0.f, 0.f, 0.f);
        if (h >= 0 && h < 32)
            xv = *(const float4*)(xb + (size_t)c * SS * HWHW + h * 32 + g * 4);
        const int colb = 1 + g * 4;
        xs[r][colb + 0][c] = f2bf(xv.x);
        xs[r][colb + 1][c] = f2bf(xv.y);
        xs[r][colb + 2][c] = f2bf(xv.z);
        xs[r][colb + 3][c] = f2bf(xv.w);
    }
    __syncthreads();

    const int wvid = tid >> 6;
    const int lane = tid & 63;
    const int ln   = lane & 31;
    const int lh   = lane >> 5;
    const int nt0  = wvid * 2;             // wave covers rows nt0, nt0+1 of chunk

    f32x16 acc[3][2];
#pragma unroll
    for (int m = 0; m < 3; ++m)
#pragma unroll
        for (int n = 0; n < 2; ++n)
#pragma unroll
            for (int i = 0; i < 16; ++i) acc[m][n][i] = 0.f;

#pragma unroll 1
    for (int tap = 0; tap < 9; ++tap) {
        const int dh = tap / 3;
        const int dw = tap % 3;
        const ushort_t* wtap = wt + (size_t)tap * 96 * 64;
#pragma unroll
        for (int kc = 0; kc < 4; ++kc) {
            const int c0 = kc * 16 + lh * 8;
            const bf16x8 a0 = *(const bf16x8*)(wtap + (((size_t)ln      ) << 6) + c0);
            const bf16x8 a1 = *(const bf16x8*)(wtap + (((size_t)ln + 32 ) << 6) + c0);
            const bf16x8 a2 = *(const bf16x8*)(wtap + (((size_t)ln + 64 ) << 6) + c0);
            const bf16x8 b0 = *(const bf16x8*)&xs[nt0 + dh    ][ln + dw][c0];
            const bf16x8 b1 = *(const bf16x8*)&xs[nt0 + 1 + dh][ln + dw][c0];
            acc[0][0] = __builtin_amdgcn_mfma_f32_32x32x16_bf16(a0, b0, acc[0][0], 0, 0, 0);
            acc[0][1] = __builtin_amdgcn_mfma_f32_32x32x16_bf16(a0, b1, acc[0][1], 0, 0, 0);
            acc[1][0] = __builtin_amdgcn_mfma_f32_32x32x16_bf16(a1, b0, acc[1][0], 0, 0, 0);
            acc[1][1] = __builtin_amdgcn_mfma_f32_32x32x16_bf16(a1, b1, acc[1][1], 0, 0, 0);
            acc[2][0] = __builtin_amdgcn_mfma_f32_32x32x16_bf16(a2, b0, acc[2][0], 0, 0, 0);
            acc[2][1] = __builtin_amdgcn_mfma_f32_32x32x16_bf16(a2, b1, acc[2][1], 0, 0, 0);
        }
    }

    // epilogue: C/D layout col=lane&31 (pixel), row m=(r&3)+8*(r>>2)+4*lh (oc)
    const float* biases[3] = {bq, bk, bv};
#pragma unroll
    for (int mt = 0; mt < 3; ++mt) {
        const float* bptr = biases[mt];
        ushort_t* dst = qkv + (size_t)mt * QELEMS + (((size_t)b * CD) * SS + s) * HWHW;
#pragma unroll
        for (int ntl = 0; ntl < 2; ++ntl) {
            const int gp = (h0 + nt0 + ntl) * 32 + ln;
#pragma unroll
            for (int r = 0; r < 16; ++r) {
                const int m = (r & 3) + 8 * (r >> 2) + 4 * lh;
                const float val = acc[mt][ntl][r] + bptr[m];
                dst[(size_t)m * SS * HWHW + gp] = f2bf(val);
            }
        }
    }
}

// ---------------------------------------------------------------------------
// Kernel 2: per-(b,c) attention (unchanged from round 1).
// ---------------------------------------------------------------------------
__global__ __launch_bounds__(256) void attn_kernel(ushort_t* __restrict__ qkv)
{
    __shared__ float    scb[64][65];
    __shared__ ushort_t qch[64][132];
    __shared__ ushort_t kch[64][132];

    const int tid = threadIdx.x;
    const int bc  = blockIdx.x;
    ushort_t* qbase = qkv + (size_t)bc * SS * HWHW;
    const ushort_t* kbase = qbase + QELEMS;
    const ushort_t* vbase = qbase + 2 * (size_t)QELEMS;

    const int ty = tid >> 4, tx = tid & 15;
    const int sy = ty * 4, sx = tx * 4;

    float acc[4][4];
#pragma unroll
    for (int i = 0; i < 4; ++i)
#pragma unroll
        for (int j = 0; j < 4; ++j) acc[i][j] = 0.0f;

    for (int fc = 0; fc < 8; ++fc) {
        __syncthreads();
#pragma unroll
        for (int u = 0; u < 8; ++u) {
            const int unit = tid + u * 256;
            const int row  = unit >> 5;
            const int col  = (unit & 31) * 4;
            const ushort4 qa = *(const ushort4*)(qbase + (size_t)row * HWHW + fc * 128 + col);
            const ushort4 ka = *(const ushort4*)(kbase + (size_t)row * HWHW + fc * 128 + col);
            *(ushort4*)&qch[row][col] = qa;
            *(ushort4*)&kch[row][col] = ka;
        }
        __syncthreads();

        for (int f = 0; f < 128; f += 2) {
            float q0[4], q1[4], k0[4], k1[4];
#pragma unroll
            for (int i = 0; i < 4; ++i) {
                const unsigned int qp = *(const unsigned int*)&qch[sy + i][f];
                q0[i] = bf2f((ushort_t)(qp & 0xffffu));
                q1[i] = bf2f((ushort_t)(qp >> 16));
                const unsigned int kp = *(const unsigned int*)&kch[sx + i][f];
                k0[i] = bf2f((ushort_t)(kp & 0xffffu));
                k1[i] = bf2f((ushort_t)(kp >> 16));
            }
#pragma unroll
            for (int i = 0; i < 4; ++i)
#pragma unroll
                for (int j = 0; j < 4; ++j)
                    acc[i][j] += q0[i] * k0[j] + q1[i] * k1[j];
        }
    }

    const float scale = 0.03125f;
#pragma unroll
    for (int i = 0; i < 4; ++i)
#pragma unroll
        for (int j = 0; j < 4; ++j) {
            const float xv = acc[i][j] * scale;
            scb[sy + i][sx + j] = 1.0f / (1.0f + __expf(-xv));
        }
    __syncthreads();

    const int fcol = tid * 4;
#pragma unroll 1
    for (int gIdx = 0; gIdx < 4; ++gIdx) {
        float o[16][4];
#pragma unroll
        for (int i = 0; i < 16; ++i)
#pragma unroll
            for (int j = 0; j < 4; ++j) o[i][j] = 0.0f;

        for (int t = 0; t < 64; ++t) {
            const ushort4 va = *(const ushort4*)(vbase + (size_t)t * HWHW + fcol);
            const float v0 = bf2f(va.x), v1 = bf2f(va.y), v2 = bf2f(va.z), v3 = bf2f(va.w);
#pragma unroll
            for (int i = 0; i < 16; ++i) {
                const float a = scb[gIdx * 16 + i][t];
                o[i][0] += a * v0;
                o[i][1] += a * v1;
                o[i][2] += a * v2;
                o[i][3] += a * v3;
            }
        }
#pragma unroll
        for (int i = 0; i < 16; ++i) {
            const int srow = gIdx * 16 + i;
            ushort4 u;
            u.x = f2bf(o[i][0]);
            u.y = f2bf(o[i][1]);
            u.z = f2bf(o[i][2]);
            u.w = f2bf(o[i][3]);
            *(ushort4*)(qbase + (size_t)srow * HWHW + fcol) = u;
        }
    }
}

// ---------------------------------------------------------------------------
// Kernel 3: final conv (Cd=32 -> C=64) via implicit-GEMM MFMA, fp32 out.
// ---------------------------------------------------------------------------
__global__ __launch_bounds__(256) void conv_out_mfma(
    const ushort_t* __restrict__ att,
    const ushort_t* __restrict__ wt2,
    const float* __restrict__ bo,
    float* __restrict__ out)
{
    __shared__ ushort_t xs[10][34][40];   // 27200 B

    const int tid   = threadIdx.x;
    const int bs    = blockIdx.x >> 2;
    const int chunk = blockIdx.x & 3;
    const int b     = bs >> 6;
    const int s     = bs & 63;
    const int h0    = chunk * 8;

    if (tid < 80) {
        const int r    = tid >> 3;
        const int rest = tid & 7;
        const int col  = (rest >> 2) ? 33 : 0;
        const int c0   = (rest & 3) << 3;
        bf16x8 z = {0, 0, 0, 0, 0, 0, 0, 0};
        *(bf16x8*)&xs[r][col][c0] = z;
    }

    const ushort_t* ab = att + ((size_t)b * CD * SS + s) * HWHW;
#pragma unroll
    for (int it = 0; it < 10; ++it) {
        const int u  = tid + it * 256;      // 0..2559 = 32c * 10r * 8grp
        const int g  = u & 7;
        const int t2 = u >> 3;              // 0..319
        const int r  = t2 % 10;
        const int c  = t2 / 10;
        const int h  = h0 - 1 + r;
        ushort4 xv = make_ushort4(0, 0, 0, 0);
        if (h >= 0 && h < 32)
            xv = *(const ushort4*)(ab + (size_t)c * SS * HWHW + h * 32 + g * 4);
        const int colb = 1 + g * 4;
        xs[r][colb + 0][c] = xv.x;
        xs[r][colb + 1][c] = xv.y;
        xs[r][colb + 2][c] = xv.z;
        xs[r][colb + 3][c] = xv.w;
    }
    __syncthreads();

    const int wvid = tid >> 6;
    const int lane = tid & 63;
    const int ln   = lane & 31;
    const int lh   = lane >> 5;
    const int nt0  = wvid * 2;

    f32x16 acc[2][2];
#pragma unroll
    for (int m = 0; m < 2; ++m)
#pragma unroll
        for (int n = 0; n < 2; ++n)
#pragma unroll
            for (int i = 0; i < 16; ++i) acc[m][n][i] = 0.f;

#pragma unroll 1
    for (int tap = 0; tap < 9; ++tap) {
        const int dh = tap / 3;
        const int dw = tap % 3;
        const ushort_t* wtap = wt2 + (size_t)tap * 64 * 32;
#pragma unroll
        for (int kc = 0; kc < 2; ++kc) {
            const int c0 = kc * 16 + lh * 8;
            const bf16x8 a0 = *(const bf16x8*)(wtap + (((size_t)ln      ) << 5) + c0);
            const bf16x8 a1 = *(const bf16x8*)(wtap + (((size_t)ln + 32 ) << 5) + c0);
            const bf16x8 b0 = *(const bf16x8*)&xs[nt0 + dh    ][ln + dw][c0];
            const bf16x8 b1 = *(const bf16x8*)&xs[nt0 + 1 + dh][ln + dw][c0];
            acc[0][0] = __builtin_amdgcn_mfma_f32_32x32x16_bf16(a0, b0, acc[0][0], 0, 0, 0);
            acc[0][1] = __builtin_amdgcn_mfma_f32_32x32x16_bf16(a0, b1, acc[0][1], 0, 0, 0);
            acc[1][0] = __builtin_amdgcn_mfma_f32_32x32x16_bf16(a1, b0, acc[1][0], 0, 0, 0);
            acc[1][1] = __builtin_amdgcn_mfma_f32_32x32x16_bf16(a1, b1, acc[1][1], 0, 0, 0);
        }
    }

#pragma unroll
    for (int mt = 0; mt < 2; ++mt) {
        float* dst = out + (((size_t)b * CC + mt * 32) * SS + s) * HWHW;
#pragma unroll
        for (int ntl = 0; ntl < 2; ++ntl) {
            const int gp = (h0 + nt0 + ntl) * 32 + ln;
#pragma unroll
            for (int r = 0; r < 16; ++r) {
                const int m = (r & 3) + 8 * (r >> 2) + 4 * lh;
                dst[(size_t)m * SS * HWHW + gp] = acc[mt][ntl][r] + bo[mt * 32 + m];
            }
        }
    }
}

extern "C" void kernel_launch(void* const* d_in, const int* in_sizes, int n_in,
                              void* d_out, int out_size, void* d_ws, size_t ws_size,
                              hipStream_t stream)
{
    const float* x  = (const float*)d_in[0];
    const float* wq = (const float*)d_in[1];
    const float* bq = (const float*)d_in[2];
    const float* wk = (const float*)d_in[3];
    const float* bk = (const float*)d_in[4];
    const float* wv = (const float*)d_in[5];
    const float* bv = (const float*)d_in[6];
    const float* wo = (const float*)d_in[7];
    const float* bo = (const float*)d_in[8];
    float* out = (float*)d_out;

    ushort_t* qkv = (ushort_t*)d_ws;                                   // 192 MiB
    ushort_t* wt  = (ushort_t*)((char*)d_ws + (size_t)3 * QELEMS * 2); // 108 KiB
    ushort_t* wt2 = wt + 9 * 96 * 64;                                  // 36 KiB

    pack_weights<<<288, 256, 0, stream>>>(wq, wk, wv, wo, wt, wt2);
    conv_qkv_mfma<<<dim3(BB * SS * 4), 256, 0, stream>>>(x, wt, bq, bk, bv, qkv);
    attn_kernel<<<dim3(BB * CD), 256, 0, stream>>>(qkv);
    conv_out_mfma<<<dim3(BB * SS * 4), 256, 0, stream>>>(qkv, wt2, bo, out);
}

// Round 2
// 1028.135 us; speedup vs baseline: 1.0535x; 1.0535x over previous
//
#include <hip/hip_runtime.h>
#include <hip/hip_bf16.h>

#define BB   16
#define CC   64
#define SS   64
#define HWHW 1024
#define CD   32
#define QELEMS (BB * CD * SS * HWHW) /* 33554432 elems per q/k/v tensor */

typedef unsigned short ushort_t;
typedef __attribute__((ext_vector_type(8)))  short bf16x8;
typedef __attribute__((ext_vector_type(16))) float f32x16;

static __device__ inline float bf2f(ushort_t u) {
    union { float f; unsigned int i; } v;
    v.i = ((unsigned int)u) << 16;
    return v.f;
}
static __device__ inline ushort_t f2bf(float f) {
    union { float f; unsigned int i; } v;
    v.f = f;
    unsigned int x = v.i;
    return (ushort_t)((x + 0x7fffu + ((x >> 16) & 1u)) >> 16);
}

// ---------------------------------------------------------------------------
// Pack weights: Wt[tap][oc(96: q|k|v)][c(64)] bf16 and Wt2[tap][oc(64)][c(32)]
// so MFMA A-fragments (8 consecutive c) are single 16B loads.
// ---------------------------------------------------------------------------
__global__ __launch_bounds__(256) void pack_weights(
    const float* __restrict__ wq, const float* __restrict__ wk,
    const float* __restrict__ wv, const float* __restrict__ wo,
    ushort_t* __restrict__ wt, ushort_t* __restrict__ wt2)
{
    const int d = blockIdx.x * 256 + threadIdx.x;
    if (d < 9 * 96 * 64) {
        const int tap = d / (96 * 64);
        const int rem = d % (96 * 64);
        const int oc  = rem >> 6;
        const int c   = rem & 63;
        const float* wsrc = (oc < 32) ? wq : (oc < 64) ? wk : wv;
        const int ocl = oc & 31;
        wt[d] = f2bf(wsrc[((size_t)ocl * 64 + c) * 9 + tap]);
    }
    const int d2 = d - 9 * 96 * 64;
    if (d2 >= 0 && d2 < 9 * 64 * 32) {
        const int tap = d2 / (64 * 32);
        const int rem = d2 % (64 * 32);
        const int oc  = rem >> 5;
        const int c   = rem & 31;
        wt2[d2] = f2bf(wo[((size_t)oc * 32 + c) * 9 + tap]);
    }
}

// ---------------------------------------------------------------------------
// NEW Kernel 0: transpose x fp32 [b][c][s][px] -> xT bf16 [b][s][px][c].
// One block per (b,s); 8 chunks of 128 px via LDS tile. Memory-streaming.
// ---------------------------------------------------------------------------
__global__ __launch_bounds__(256) void transpose_x(
    const float* __restrict__ x, ushort_t* __restrict__ xT)
{
    __shared__ ushort_t t[64][132];   // [c][px128 +4 pad] = 16896 B

    const int bs  = blockIdx.x;       // b*64 + s
    const int b   = bs >> 6;
    const int s   = bs & 63;
    const int tid = threadIdx.x;
    const float* xb = x + ((size_t)b * CC * SS + s) * HWHW;
    ushort_t*    xo = xT + (size_t)bs * HWHW * CC;

    for (int fc = 0; fc < 8; ++fc) {
        __syncthreads();
#pragma unroll
        for (int i = 0; i < 8; ++i) {
            const int u  = tid + i * 256;   // 0..2047 = 64c * 32 f4
            const int c  = u >> 5;
            const int f4 = u & 31;
            const float4 v = *(const float4*)(xb + (size_t)c * SS * HWHW + fc * 128 + f4 * 4);
            const unsigned int lo = (unsigned int)f2bf(v.x) | ((unsigned int)f2bf(v.y) << 16);
            const unsigned int hi = (unsigned int)f2bf(v.z) | ((unsigned int)f2bf(v.w) << 16);
            *(uint2*)&t[c][f4 * 4] = make_uint2(lo, hi);
        }
        __syncthreads();
#pragma unroll
        for (int i = 0; i < 4; ++i) {
            const int u  = tid + i * 256;   // 0..1023 = 128px * 8cgr
            const int px = u >> 3;
            const int cg = (u & 7) * 8;
            bf16x8 vv;
#pragma unroll
            for (int j = 0; j < 8; ++j) vv[j] = (short)t[cg + j][px];
            *(bf16x8*)(xo + (size_t)(fc * 128 + px) * CC + cg) = vv;
        }
    }
}

// ---------------------------------------------------------------------------
// NEW Kernel 2.5: transpose att bf16 [b][c32][s][f] -> attT bf16 [b][s][px][c32].
// ---------------------------------------------------------------------------
__global__ __launch_bounds__(256) void transpose_att(
    const ushort_t* __restrict__ att, ushort_t* __restrict__ attT)
{
    __shared__ ushort_t t[32][260];   // [c][px256 +4 pad] = 16640 B

    const int bs  = blockIdx.x;       // b*64 + s
    const int b   = bs >> 6;
    const int s   = bs & 63;
    const int tid = threadIdx.x;
    const ushort_t* ab = att + ((size_t)b * CD * SS + s) * HWHW;
    ushort_t*       ao = attT + (size_t)bs * HWHW * CD;

    for (int fc = 0; fc < 4; ++fc) {
        __syncthreads();
#pragma unroll
        for (int i = 0; i < 8; ++i) {
            const int u  = tid + i * 256;   // 0..2047 = 32c * 64 u4
            const int c  = u >> 6;
            const int f4 = u & 63;
            const ushort4 v = *(const ushort4*)(ab + (size_t)c * SS * HWHW + fc * 256 + f4 * 4);
            *(ushort4*)&t[c][f4 * 4] = v;
        }
        __syncthreads();
#pragma unroll
        for (int i = 0; i < 4; ++i) {
            const int u  = tid + i * 256;   // 0..1023 = 256px * 4cgr
            const int px = u >> 2;
            const int cg = (u & 3) * 8;
            bf16x8 vv;
#pragma unroll
            for (int j = 0; j < 8; ++j) vv[j] = (short)t[cg + j][px];
            *(bf16x8*)(ao + (size_t)(fc * 256 + px) * CD + cg) = vv;
        }
    }
}

// ---------------------------------------------------------------------------
// Kernel 1: fused q/k/v conv via implicit-GEMM MFMA.
// Block: one (b, s, 8-row pixel chunk). M=96 (q|k|v x32ch), N=256 px, K=64x9.
// LDS x tile: pixel-major [row 10][col 34][c 72pad] bf16, halo zero-padded.
// Staging now reads pre-transposed bf16 xT: one ds_write_b128 per granule.
// ---------------------------------------------------------------------------
__global__ __launch_bounds__(256) void conv_qkv_mfma(
    const ushort_t* __restrict__ xT,
    const ushort_t* __restrict__ wt,
    const float* __restrict__ bq, const float* __restrict__ bk,
    const float* __restrict__ bv,
    ushort_t* __restrict__ qkv)
{
    __shared__ ushort_t xs[10][34][72];   // 48960 B

    const int tid   = threadIdx.x;
    const int bs    = blockIdx.x >> 2;
    const int chunk = blockIdx.x & 3;
    const int b     = bs >> 6;
    const int s     = bs & 63;
    const int h0    = chunk * 8;

    // zero the halo columns (col 0 and 33), c in [0,64)
    if (tid < 160) {
        const int r    = tid >> 4;
        const int rest = tid & 15;
        const int col  = (rest >> 3) ? 33 : 0;
        const int c0   = (rest & 7) << 3;
        bf16x8 z = {0, 0, 0, 0, 0, 0, 0, 0};
        *(bf16x8*)&xs[r][col][c0] = z;
    }

    // stage rows h0-1 .. h0+8 from xT (bf16 pixel-major), zeros outside image
    const ushort_t* xb = xT + (size_t)bs * HWHW * CC;
    {
        const int w  = tid >> 3;          // 0..31
        const int cg = (tid & 7) * 8;     // 0..56
#pragma unroll
        for (int it = 0; it < 10; ++it) {
            const int h = h0 - 1 + it;
            bf16x8 v = {0, 0, 0, 0, 0, 0, 0, 0};
            if (h >= 0 && h < 32)
                v = *(const bf16x8*)(xb + (size_t)(h * 32 + w) * CC + cg);
            *(bf16x8*)&xs[it][1 + w][cg] = v;
        }
    }
    __syncthreads();

    const int wvid = tid >> 6;
    const int lane = tid & 63;
    const int ln   = lane & 31;
    const int lh   = lane >> 5;
    const int nt0  = wvid * 2;             // wave covers rows nt0, nt0+1 of chunk

    f32x16 acc[3][2];
#pragma unroll
    for (int m = 0; m < 3; ++m)
#pragma unroll
        for (int n = 0; n < 2; ++n)
#pragma unroll
            for (int i = 0; i < 16; ++i) acc[m][n][i] = 0.f;

#pragma unroll 1
    for (int tap = 0; tap < 9; ++tap) {
        const int dh = tap / 3;
        const int dw = tap % 3;
        const ushort_t* wtap = wt + (size_t)tap * 96 * 64;
#pragma unroll
        for (int kc = 0; kc < 4; ++kc) {
            const int c0 = kc * 16 + lh * 8;
            const bf16x8 a0 = *(const bf16x8*)(wtap + (((size_t)ln      ) << 6) + c0);
            const bf16x8 a1 = *(const bf16x8*)(wtap + (((size_t)ln + 32 ) << 6) + c0);
            const bf16x8 a2 = *(const bf16x8*)(wtap + (((size_t)ln + 64 ) << 6) + c0);
            const bf16x8 b0 = *(const bf16x8*)&xs[nt0 + dh    ][ln + dw][c0];
            const bf16x8 b1 = *(const bf16x8*)&xs[nt0 + 1 + dh][ln + dw][c0];
            acc[0][0] = __builtin_amdgcn_mfma_f32_32x32x16_bf16(a0, b0, acc[0][0], 0, 0, 0);
            acc[0][1] = __builtin_amdgcn_mfma_f32_32x32x16_bf16(a0, b1, acc[0][1], 0, 0, 0);
            acc[1][0] = __builtin_amdgcn_mfma_f32_32x32x16_bf16(a1, b0, acc[1][0], 0, 0, 0);
            acc[1][1] = __builtin_amdgcn_mfma_f32_32x32x16_bf16(a1, b1, acc[1][1], 0, 0, 0);
            acc[2][0] = __builtin_amdgcn_mfma_f32_32x32x16_bf16(a2, b0, acc[2][0], 0, 0, 0);
            acc[2][1] = __builtin_amdgcn_mfma_f32_32x32x16_bf16(a2, b1, acc[2][1], 0, 0, 0);
        }
    }

    // epilogue: C/D layout col=lane&31 (pixel), row m=(r&3)+8*(r>>2)+4*lh (oc)
    const float* biases[3] = {bq, bk, bv};
#pragma unroll
    for (int mt = 0; mt < 3; ++mt) {
        const float* bptr = biases[mt];
        ushort_t* dst = qkv + (size_t)mt * QELEMS + (((size_t)b * CD) * SS + s) * HWHW;
#pragma unroll
        for (int ntl = 0; ntl < 2; ++ntl) {
            const int gp = (h0 + nt0 + ntl) * 32 + ln;
#pragma unroll
            for (int r = 0; r < 16; ++r) {
                const int m = (r & 3) + 8 * (r >> 2) + 4 * lh;
                const float val = acc[mt][ntl][r] + bptr[m];
                dst[(size_t)m * SS * HWHW + gp] = f2bf(val);
            }
        }
    }
}

// ---------------------------------------------------------------------------
// Kernel 2: per-(b,c) attention (unchanged).
// ---------------------------------------------------------------------------
__global__ __launch_bounds__(256) void attn_kernel(ushort_t* __restrict__ qkv)
{
    __shared__ float    scb[64][65];
    __shared__ ushort_t qch[64][132];
    __shared__ ushort_t kch[64][132];

    const int tid = threadIdx.x;
    const int bc  = blockIdx.x;
    ushort_t* qbase = qkv + (size_t)bc * SS * HWHW;
    const ushort_t* kbase = qbase + QELEMS;
    const ushort_t* vbase = qbase + 2 * (size_t)QELEMS;

    const int ty = tid >> 4, tx = tid & 15;
    const int sy = ty * 4, sx = tx * 4;

    float acc[4][4];
#pragma unroll
    for (int i = 0; i < 4; ++i)
#pragma unroll
        for (int j = 0; j < 4; ++j) acc[i][j] = 0.0f;

    for (int fc = 0; fc < 8; ++fc) {
        __syncthreads();
#pragma unroll
        for (int u = 0; u < 8; ++u) {
            const int unit = tid + u * 256;
            const int row  = unit >> 5;
            const int col  = (unit & 31) * 4;
            const ushort4 qa = *(const ushort4*)(qbase + (size_t)row * HWHW + fc * 128 + col);
            const ushort4 ka = *(const ushort4*)(kbase + (size_t)row * HWHW + fc * 128 + col);
            *(ushort4*)&qch[row][col] = qa;
            *(ushort4*)&kch[row][col] = ka;
        }
        __syncthreads();

        for (int f = 0; f < 128; f += 2) {
            float q0[4], q1[4], k0[4], k1[4];
#pragma unroll
            for (int i = 0; i < 4; ++i) {
                const unsigned int qp = *(const unsigned int*)&qch[sy + i][f];
                q0[i] = bf2f((ushort_t)(qp & 0xffffu));
                q1[i] = bf2f((ushort_t)(qp >> 16));
                const unsigned int kp = *(const unsigned int*)&kch[sx + i][f];
                k0[i] = bf2f((ushort_t)(kp & 0xffffu));
                k1[i] = bf2f((ushort_t)(kp >> 16));
            }
#pragma unroll
            for (int i = 0; i < 4; ++i)
#pragma unroll
                for (int j = 0; j < 4; ++j)
                    acc[i][j] += q0[i] * k0[j] + q1[i] * k1[j];
        }
    }

    const float scale = 0.03125f;
#pragma unroll
    for (int i = 0; i < 4; ++i)
#pragma unroll
        for (int j = 0; j < 4; ++j) {
            const float xv = acc[i][j] * scale;
            scb[sy + i][sx + j] = 1.0f / (1.0f + __expf(-xv));
        }
    __syncthreads();

    const int fcol = tid * 4;
#pragma unroll 1
    for (int gIdx = 0; gIdx < 4; ++gIdx) {
        float o[16][4];
#pragma unroll
        for (int i = 0; i < 16; ++i)
#pragma unroll
            for (int j = 0; j < 4; ++j) o[i][j] = 0.0f;

        for (int t = 0; t < 64; ++t) {
            const ushort4 va = *(const ushort4*)(vbase + (size_t)t * HWHW + fcol);
            const float v0 = bf2f(va.x), v1 = bf2f(va.y), v2 = bf2f(va.z), v3 = bf2f(va.w);
#pragma unroll
            for (int i = 0; i < 16; ++i) {
                const float a = scb[gIdx * 16 + i][t];
                o[i][0] += a * v0;
                o[i][1] += a * v1;
                o[i][2] += a * v2;
                o[i][3] += a * v3;
            }
        }
#pragma unroll
        for (int i = 0; i < 16; ++i) {
            const int srow = gIdx * 16 + i;
            ushort4 u;
            u.x = f2bf(o[i][0]);
            u.y = f2bf(o[i][1]);
            u.z = f2bf(o[i][2]);
            u.w = f2bf(o[i][3]);
            *(ushort4*)(qbase + (size_t)srow * HWHW + fcol) = u;
        }
    }
}

// ---------------------------------------------------------------------------
// Kernel 3: final conv (Cd=32 -> C=64) via implicit-GEMM MFMA, fp32 out.
// Staging now reads pre-transposed attT: one ds_write_b128 per granule.
// ---------------------------------------------------------------------------
__global__ __launch_bounds__(256) void conv_out_mfma(
    const ushort_t* __restrict__ attT,
    const ushort_t* __restrict__ wt2,
    const float* __restrict__ bo,
    float* __restrict__ out)
{
    __shared__ ushort_t xs[10][34][40];   // 27200 B

    const int tid   = threadIdx.x;
    const int bs    = blockIdx.x >> 2;
    const int chunk = blockIdx.x & 3;
    const int b     = bs >> 6;
    const int s     = bs & 63;
    const int h0    = chunk * 8;

    if (tid < 80) {
        const int r    = tid >> 3;
        const int rest = tid & 7;
        const int col  = (rest >> 2) ? 33 : 0;
        const int c0   = (rest & 3) << 3;
        bf16x8 z = {0, 0, 0, 0, 0, 0, 0, 0};
        *(bf16x8*)&xs[r][col][c0] = z;
    }

    const ushort_t* ab = attT + (size_t)bs * HWHW * CD;
#pragma unroll
    for (int it = 0; it < 5; ++it) {
        const int u  = tid + it * 256;    // 0..1279 = 10r * 32w * 4cgr
        const int cg = (u & 3) * 8;
        const int w  = (u >> 2) & 31;
        const int r  = u >> 7;            // 0..9 (wave-uniform)
        const int h  = h0 - 1 + r;
        bf16x8 v = {0, 0, 0, 0, 0, 0, 0, 0};
        if (h >= 0 && h < 32)
            v = *(const bf16x8*)(ab + (size_t)(h * 32 + w) * CD + cg);
        *(bf16x8*)&xs[r][1 + w][cg] = v;
    }
    __syncthreads();

    const int wvid = tid >> 6;
    const int lane = tid & 63;
    const int ln   = lane & 31;
    const int lh   = lane >> 5;
    const int nt0  = wvid * 2;

    f32x16 acc[2][2];
#pragma unroll
    for (int m = 0; m < 2; ++m)
#pragma unroll
        for (int n = 0; n < 2; ++n)
#pragma unroll
            for (int i = 0; i < 16; ++i) acc[m][n][i] = 0.f;

#pragma unroll 1
    for (int tap = 0; tap < 9; ++tap) {
        const int dh = tap / 3;
        const int dw = tap % 3;
        const ushort_t* wtap = wt2 + (size_t)tap * 64 * 32;
#pragma unroll
        for (int kc = 0; kc < 2; ++kc) {
            const int c0 = kc * 16 + lh * 8;
            const bf16x8 a0 = *(const bf16x8*)(wtap + (((size_t)ln      ) << 5) + c0);
            const bf16x8 a1 = *(const bf16x8*)(wtap + (((size_t)ln + 32 ) << 5) + c0);
            const bf16x8 b0 = *(const bf16x8*)&xs[nt0 + dh    ][ln + dw][c0];
            const bf16x8 b1 = *(const bf16x8*)&xs[nt0 + 1 + dh][ln + dw][c0];
            acc[0][0] = __builtin_amdgcn_mfma_f32_32x32x16_bf16(a0, b0, acc[0][0], 0, 0, 0);
            acc[0][1] = __builtin_amdgcn_mfma_f32_32x32x16_bf16(a0, b1, acc[0][1], 0, 0, 0);
            acc[1][0] = __builtin_amdgcn_mfma_f32_32x32x16_bf16(a1, b0, acc[1][0], 0, 0, 0);
            acc[1][1] = __builtin_amdgcn_mfma_f32_32x32x16_bf16(a1, b1, acc[1][1], 0, 0, 0);
        }
    }

#pragma unroll
    for (int mt = 0; mt < 2; ++mt) {
        float* dst = out + (((size_t)b * CC + mt * 32) * SS + s) * HWHW;
#pragma unroll
        for (int ntl = 0; ntl < 2; ++ntl) {
            const int gp = (h0 + nt0 + ntl) * 32 + ln;
#pragma unroll
            for (int r = 0; r < 16; ++r) {
                const int m = (r & 3) + 8 * (r >> 2) + 4 * lh;
                dst[(size_t)m * SS * HWHW + gp] = acc[mt][ntl][r] + bo[mt * 32 + m];
            }
        }
    }
}

extern "C" void kernel_launch(void* const* d_in, const int* in_sizes, int n_in,
                              void* d_out, int out_size, void* d_ws, size_t ws_size,
                              hipStream_t stream)
{
    const float* x  = (const float*)d_in[0];
    const float* wq = (const float*)d_in[1];
    const float* bq = (const float*)d_in[2];
    const float* wk = (const float*)d_in[3];
    const float* bk = (const float*)d_in[4];
    const float* wv = (const float*)d_in[5];
    const float* bv = (const float*)d_in[6];
    const float* wo = (const float*)d_in[7];
    const float* bo = (const float*)d_in[8];
    float* out = (float*)d_out;

    ushort_t* qkv = (ushort_t*)d_ws;                                   // 192 MiB
    ushort_t* wt  = (ushort_t*)((char*)d_ws + (size_t)3 * QELEMS * 2); // 108 KiB
    ushort_t* wt2 = wt + 9 * 96 * 64;                                  // 36 KiB
    // xT (128 MiB bf16) lives in the out buffer (256 MiB fp32), dead until conv_out.
    ushort_t* xT   = (ushort_t*)d_out;
    // attT reuses the k region (exactly QELEMS elems), dead after attn.
    ushort_t* attT = qkv + (size_t)QELEMS;

    transpose_x<<<dim3(BB * SS), 256, 0, stream>>>(x, xT);
    pack_weights<<<288, 256, 0, stream>>>(wq, wk, wv, wo, wt, wt2);
    conv_qkv_mfma<<<dim3(BB * SS * 4), 256, 0, stream>>>(xT, wt, bq, bk, bv, qkv);
    attn_kernel<<<dim3(BB * CD), 256, 0, stream>>>(qkv);
    transpose_att<<<dim3(BB * SS), 256, 0, stream>>>(qkv, attT);
    conv_out_mfma<<<dim3(BB * SS * 4), 256, 0, stream>>>(attT, wt2, bo, out);
}

// Round 3
// 905.541 us; speedup vs baseline: 1.1961x; 1.1354x over previous
//
#include <hip/hip_runtime.h>
#include <hip/hip_bf16.h>

#define BB   16
#define CC   64
#define SS   64
#define HWHW 1024
#define CD   32
#define QELEMS (BB * CD * SS * HWHW) /* 33554432 elems per q/k/v tensor */

typedef unsigned short ushort_t;
typedef __attribute__((ext_vector_type(8)))  short bf16x8;
typedef __attribute__((ext_vector_type(16))) float f32x16;

static __device__ inline float bf2f(ushort_t u) {
    union { float f; unsigned int i; } v;
    v.i = ((unsigned int)u) << 16;
    return v.f;
}
static __device__ inline ushort_t f2bf(float f) {
    union { float f; unsigned int i; } v;
    v.f = f;
    unsigned int x = v.i;
    return (ushort_t)((x + 0x7fffu + ((x >> 16) & 1u)) >> 16);
}

static __device__ inline void gload_lds16(const ushort_t* g, ushort_t* l) {
    __builtin_amdgcn_global_load_lds(
        (const __attribute__((address_space(1))) void*)g,
        (__attribute__((address_space(3))) void*)l, 16, 0, 0);
}

// ---------------------------------------------------------------------------
// Pack weights, coalesced layout:
//   wt [tap][mt(3)][kc(4)][lane(64)][8]  (fragment = contiguous 1KB per wave)
//   wt2[tap][mt(2)][kc(2)][lane(64)][8]
// lane -> (ocl = lane&31, chalf = lane>>5); c = kc*16 + chalf*8 + e.
// ---------------------------------------------------------------------------
__global__ __launch_bounds__(256) void pack_weights(
    const float* __restrict__ wq, const float* __restrict__ wk,
    const float* __restrict__ wv, const float* __restrict__ wo,
    ushort_t* __restrict__ wt, ushort_t* __restrict__ wt2)
{
    const int d = blockIdx.x * 256 + threadIdx.x;
    if (d < 9 * 3 * 4 * 512) {
        const int e    = d & 7;
        const int lane = (d >> 3) & 63;
        const int kc   = (d >> 9) & 3;
        const int mt   = (d >> 11) % 3;
        const int tap  = d / 6144;
        const int ocl  = lane & 31;
        const int c    = kc * 16 + (lane >> 5) * 8 + e;
        const float* wsrc = (mt == 0) ? wq : (mt == 1) ? wk : wv;
        wt[d] = f2bf(wsrc[((size_t)ocl * 64 + c) * 9 + tap]);
    }
    const int d2 = d - 9 * 3 * 4 * 512;
    if (d2 >= 0 && d2 < 9 * 2 * 2 * 512) {
        const int e    = d2 & 7;
        const int lane = (d2 >> 3) & 63;
        const int kc   = (d2 >> 9) & 1;
        const int mt   = (d2 >> 10) & 1;
        const int tap  = d2 / 2048;
        const int oc   = mt * 32 + (lane & 31);
        const int c    = kc * 16 + (lane >> 5) * 8 + e;
        wt2[d2] = f2bf(wo[((size_t)oc * 32 + c) * 9 + tap]);
    }
}

// ---------------------------------------------------------------------------
// Kernel 0: transpose x fp32 [b][c][s][px] -> xT bf16 [b][s][px][c-swizzled].
// Swizzle baked for conv_qkv's global_load_lds: granule g of pixel w stored
// at slot g ^ ((1+(px&31))&7), so linear LDS writes yield swizzled tiles.
// ---------------------------------------------------------------------------
__global__ __launch_bounds__(256) void transpose_x(
    const float* __restrict__ x, ushort_t* __restrict__ xT)
{
    __shared__ ushort_t t[64][132];   // [c][px128 +4 pad]

    const int bs  = blockIdx.x;       // b*64 + s
    const int b   = bs >> 6;
    const int s   = bs & 63;
    const int tid = threadIdx.x;
    const float* xb = x + ((size_t)b * CC * SS + s) * HWHW;
    ushort_t*    xo = xT + (size_t)bs * HWHW * CC;

    for (int fc = 0; fc < 8; ++fc) {
        __syncthreads();
#pragma unroll
        for (int i = 0; i < 8; ++i) {
            const int u  = tid + i * 256;   // 0..2047 = 64c * 32 f4
            const int c  = u >> 5;
            const int f4 = u & 31;
            const float4 v = *(const float4*)(xb + (size_t)c * SS * HWHW + fc * 128 + f4 * 4);
            const unsigned int lo = (unsigned int)f2bf(v.x) | ((unsigned int)f2bf(v.y) << 16);
            const unsigned int hi = (unsigned int)f2bf(v.z) | ((unsigned int)f2bf(v.w) << 16);
            *(uint2*)&t[c][f4 * 4] = make_uint2(lo, hi);
        }
        __syncthreads();
#pragma unroll
        for (int i = 0; i < 4; ++i) {
            const int u  = tid + i * 256;   // 0..1023 = 128px * 8cgr
            const int px = fc * 128 + (u >> 3);
            const int g  = u & 7;           // channel granule (8 ch)
            bf16x8 vv;
#pragma unroll
            for (int j = 0; j < 8; ++j) vv[j] = (short)t[g * 8 + j][u >> 3];
            const int slot = g ^ ((1 + (px & 31)) & 7);
            *(bf16x8*)(xo + (size_t)px * CC + slot * 8) = vv;
        }
    }
}

// ---------------------------------------------------------------------------
// Kernel 2.5: transpose att bf16 [b][c32][s][f] -> attT bf16 [b][s][px][c32].
// ---------------------------------------------------------------------------
__global__ __launch_bounds__(256) void transpose_att(
    const ushort_t* __restrict__ att, ushort_t* __restrict__ attT)
{
    __shared__ ushort_t t[32][260];

    const int bs  = blockIdx.x;
    const int b   = bs >> 6;
    const int s   = bs & 63;
    const int tid = threadIdx.x;
    const ushort_t* ab = att + ((size_t)b * CD * SS + s) * HWHW;
    ushort_t*       ao = attT + (size_t)bs * HWHW * CD;

    for (int fc = 0; fc < 4; ++fc) {
        __syncthreads();
#pragma unroll
        for (int i = 0; i < 8; ++i) {
            const int u  = tid + i * 256;
            const int c  = u >> 6;
            const int f4 = u & 63;
            const ushort4 v = *(const ushort4*)(ab + (size_t)c * SS * HWHW + fc * 256 + f4 * 4);
            *(ushort4*)&t[c][f4 * 4] = v;
        }
        __syncthreads();
#pragma unroll
        for (int i = 0; i < 4; ++i) {
            const int u  = tid + i * 256;
            const int px = u >> 2;
            const int cg = (u & 3) * 8;
            bf16x8 vv;
#pragma unroll
            for (int j = 0; j < 8; ++j) vv[j] = (short)t[cg + j][px];
            *(bf16x8*)(ao + (size_t)(fc * 256 + px) * CD + cg) = vv;
        }
    }
}

// ---------------------------------------------------------------------------
// Kernel 1: fused q/k/v conv, implicit-GEMM MFMA. M=96, N=256 px, K=576.
// LDS x tile: linear [10][34][64] (XOR-swizzled content via pre-swizzled xT),
// staged by global_load_lds (16B). Coalesced weight fragments.
// ---------------------------------------------------------------------------
__global__ __launch_bounds__(256, 3) void conv_qkv_mfma(
    const ushort_t* __restrict__ xT,
    const ushort_t* __restrict__ wt,
    const float* __restrict__ bq, const float* __restrict__ bk,
    const float* __restrict__ bv,
    ushort_t* __restrict__ qkv)
{
    __shared__ ushort_t xs[10 * 34 * 64];   // 43520 B, linear

    const int tid  = threadIdx.x;
    const int nwg8 = gridDim.x >> 3;
    const int bid  = (blockIdx.x & 7) * nwg8 + (blockIdx.x >> 3);  // XCD chunking
    const int bs    = bid >> 2;
    const int chunk = bid & 3;
    const int b     = bs >> 6;
    const int s     = bs & 63;
    const int h0    = chunk * 8;

    const int wvid = tid >> 6;
    const int lane = tid & 63;
    const int ln   = lane & 31;
    const int lh   = lane >> 5;

    // zero halo cols 0 and 33 for all 10 rows (full 128B per col)
    if (tid < 160) {
        const int r    = tid >> 4;
        const int rest = tid & 15;
        const int col  = (rest >> 3) ? 33 : 0;
        const int g    = rest & 7;
        bf16x8 z = {0, 0, 0, 0, 0, 0, 0, 0};
        *(bf16x8*)&xs[(r * 34 + col) * 64 + g * 8] = z;
    }

    // stage rows h0-1 .. h0+8 from pre-swizzled xT via global_load_lds.
    // Wave wv covers bytes [wv*1024, +1024) of each 4KB row (cols 1..32).
    const ushort_t* xb = xT + (size_t)bs * HWHW * CC;
    {
        bf16x8 z = {0, 0, 0, 0, 0, 0, 0, 0};
#pragma unroll
        for (int it = 0; it < 10; ++it) {
            const int h = h0 - 1 + it;
            const int lbase = (it * 34 + 1) * 64;
            if (h >= 0 && h < 32) {
                gload_lds16(xb + (size_t)h * 2048 + wvid * 512 + lane * 8,
                            &xs[lbase + wvid * 512]);
            } else {
                *(bf16x8*)&xs[lbase + tid * 8] = z;   // zero row
            }
        }
    }
    __syncthreads();

    const int nt0 = wvid * 2;              // wave covers rows nt0, nt0+1

    f32x16 acc[3][2];
#pragma unroll
    for (int m = 0; m < 3; ++m)
#pragma unroll
        for (int n = 0; n < 2; ++n)
#pragma unroll
            for (int i = 0; i < 16; ++i) acc[m][n][i] = 0.f;

    const ushort_t* wl = wt + lane * 8;

#pragma unroll 1
    for (int tap = 0; tap < 9; ++tap) {
        const int dh = tap / 3;
        const int dw = tap % 3;
        const int col = ln + dw;
        const int czx = (col & 7) << 3;      // XOR swizzle (ushort units)
        const int r0b = ((nt0 + dh) * 34 + col) * 64;
        const int r1b = ((nt0 + 1 + dh) * 34 + col) * 64;
        const int wofs = tap * 6144;
#pragma unroll
        for (int kc = 0; kc < 4; ++kc) {
            const int c0 = kc * 16 + lh * 8;
            const int cz = c0 ^ czx;
            const bf16x8 a0 = *(const bf16x8*)(wl + wofs + kc * 512);
            const bf16x8 a1 = *(const bf16x8*)(wl + wofs + kc * 512 + 2048);
            const bf16x8 a2 = *(const bf16x8*)(wl + wofs + kc * 512 + 4096);
            const bf16x8 b0 = *(const bf16x8*)&xs[r0b + cz];
            const bf16x8 b1 = *(const bf16x8*)&xs[r1b + cz];
            acc[0][0] = __builtin_amdgcn_mfma_f32_32x32x16_bf16(a0, b0, acc[0][0], 0, 0, 0);
            acc[0][1] = __builtin_amdgcn_mfma_f32_32x32x16_bf16(a0, b1, acc[0][1], 0, 0, 0);
            acc[1][0] = __builtin_amdgcn_mfma_f32_32x32x16_bf16(a1, b0, acc[1][0], 0, 0, 0);
            acc[1][1] = __builtin_amdgcn_mfma_f32_32x32x16_bf16(a1, b1, acc[1][1], 0, 0, 0);
            acc[2][0] = __builtin_amdgcn_mfma_f32_32x32x16_bf16(a2, b0, acc[2][0], 0, 0, 0);
            acc[2][1] = __builtin_amdgcn_mfma_f32_32x32x16_bf16(a2, b1, acc[2][1], 0, 0, 0);
        }
    }

    const float* biases[3] = {bq, bk, bv};
#pragma unroll
    for (int mt = 0; mt < 3; ++mt) {
        const float* bptr = biases[mt];
        ushort_t* dst = qkv + (size_t)mt * QELEMS + (((size_t)b * CD) * SS + s) * HWHW;
#pragma unroll
        for (int ntl = 0; ntl < 2; ++ntl) {
            const int gp = (h0 + nt0 + ntl) * 32 + ln;
#pragma unroll
            for (int r = 0; r < 16; ++r) {
                const int m = (r & 3) + 8 * (r >> 2) + 4 * lh;
                const float val = acc[mt][ntl][r] + bptr[m];
                dst[(size_t)m * SS * HWHW + gp] = f2bf(val);
            }
        }
    }
}

// ---------------------------------------------------------------------------
// Kernel 2: per-(b,c) attention, vectorized LDS access.
// Thread covers S rows sy..sy+3, cols {tx, tx+16, tx+32, tx+48}.
// ---------------------------------------------------------------------------
__global__ __launch_bounds__(256) void attn_kernel(ushort_t* __restrict__ qkv)
{
    __shared__ float    scb[64][68];
    __shared__ ushort_t qch[64][136];
    __shared__ ushort_t kch[64][136];

    const int tid = threadIdx.x;
    const int bc  = blockIdx.x;
    ushort_t* qbase = qkv + (size_t)bc * SS * HWHW;
    const ushort_t* kbase = qbase + QELEMS;
    const ushort_t* vbase = qbase + 2 * (size_t)QELEMS;

    const int ty = tid >> 4, tx = tid & 15;
    const int sy = ty * 4;

    float acc[4][4];
#pragma unroll
    for (int i = 0; i < 4; ++i)
#pragma unroll
        for (int j = 0; j < 4; ++j) acc[i][j] = 0.0f;

    for (int fc = 0; fc < 8; ++fc) {
        __syncthreads();
#pragma unroll
        for (int u = 0; u < 8; ++u) {
            const int unit = tid + u * 256;
            const int row  = unit >> 5;
            const int col  = (unit & 31) * 4;
            const ushort4 qa = *(const ushort4*)(qbase + (size_t)row * HWHW + fc * 128 + col);
            const ushort4 ka = *(const ushort4*)(kbase + (size_t)row * HWHW + fc * 128 + col);
            *(ushort4*)&qch[row][col] = qa;
            *(ushort4*)&kch[row][col] = ka;
        }
        __syncthreads();

        for (int f8 = 0; f8 < 16; ++f8) {
            bf16x8 qv[4], kv[4];
#pragma unroll
            for (int i = 0; i < 4; ++i) qv[i] = *(const bf16x8*)&qch[sy + i][f8 * 8];
#pragma unroll
            for (int j = 0; j < 4; ++j) kv[j] = *(const bf16x8*)&kch[tx + 16 * j][f8 * 8];
            float qf[4][8], kf[4][8];
#pragma unroll
            for (int i = 0; i < 4; ++i)
#pragma unroll
                for (int e = 0; e < 8; ++e) {
                    qf[i][e] = bf2f((ushort_t)qv[i][e]);
                    kf[i][e] = bf2f((ushort_t)kv[i][e]);
                }
#pragma unroll
            for (int i = 0; i < 4; ++i)
#pragma unroll
                for (int j = 0; j < 4; ++j)
#pragma unroll
                    for (int e = 0; e < 8; ++e)
                        acc[i][j] += qf[i][e] * kf[j][e];
        }
    }

    const float scale = 0.03125f;
#pragma unroll
    for (int i = 0; i < 4; ++i)
#pragma unroll
        for (int j = 0; j < 4; ++j) {
            const float xv = acc[i][j] * scale;
            scb[sy + i][tx + 16 * j] = 1.0f / (1.0f + __expf(-xv));
        }
    __syncthreads();

    const int fcol = tid * 4;
#pragma unroll 1
    for (int gIdx = 0; gIdx < 4; ++gIdx) {
        float o[16][4];
#pragma unroll
        for (int i = 0; i < 16; ++i)
#pragma unroll
            for (int j = 0; j < 4; ++j) o[i][j] = 0.0f;

        for (int t4 = 0; t4 < 16; ++t4) {
            float vv[4][4];
#pragma unroll
            for (int tv = 0; tv < 4; ++tv) {
                const ushort4 va = *(const ushort4*)(vbase + (size_t)(t4 * 4 + tv) * HWHW + fcol);
                vv[tv][0] = bf2f(va.x); vv[tv][1] = bf2f(va.y);
                vv[tv][2] = bf2f(va.z); vv[tv][3] = bf2f(va.w);
            }
#pragma unroll
            for (int i = 0; i < 16; ++i) {
                const float4 a = *(const float4*)&scb[gIdx * 16 + i][t4 * 4];
#pragma unroll
                for (int f = 0; f < 4; ++f)
                    o[i][f] += a.x * vv[0][f] + a.y * vv[1][f] + a.z * vv[2][f] + a.w * vv[3][f];
            }
        }
#pragma unroll
        for (int i = 0; i < 16; ++i) {
            const int srow = gIdx * 16 + i;
            ushort4 u;
            u.x = f2bf(o[i][0]);
            u.y = f2bf(o[i][1]);
            u.z = f2bf(o[i][2]);
            u.w = f2bf(o[i][3]);
            *(ushort4*)(qbase + (size_t)srow * HWHW + fcol) = u;
        }
    }
}

// ---------------------------------------------------------------------------
// Kernel 3: final conv (Cd=32 -> C=64), implicit-GEMM MFMA, fp32 out.
// Coalesced weight fragments; reg-staged attT (layout unchanged).
// ---------------------------------------------------------------------------
__global__ __launch_bounds__(256, 3) void conv_out_mfma(
    const ushort_t* __restrict__ attT,
    const ushort_t* __restrict__ wt2,
    const float* __restrict__ bo,
    float* __restrict__ out)
{
    __shared__ ushort_t xs[10][34][40];   // 27200 B

    const int tid  = threadIdx.x;
    const int nwg8 = gridDim.x >> 3;
    const int bid  = (blockIdx.x & 7) * nwg8 + (blockIdx.x >> 3);  // XCD chunking
    const int bs    = bid >> 2;
    const int chunk = bid & 3;
    const int b     = bs >> 6;
    const int s     = bs & 63;
    const int h0    = chunk * 8;

    if (tid < 80) {
        const int r    = tid >> 3;
        const int rest = tid & 7;
        const int col  = (rest >> 2) ? 33 : 0;
        const int c0   = (rest & 3) << 3;
        bf16x8 z = {0, 0, 0, 0, 0, 0, 0, 0};
        *(bf16x8*)&xs[r][col][c0] = z;
    }

    const ushort_t* ab = attT + (size_t)bs * HWHW * CD;
#pragma unroll
    for (int it = 0; it < 5; ++it) {
        const int u  = tid + it * 256;    // 0..1279 = 10r * 32w * 4cgr
        const int cg = (u & 3) * 8;
        const int w  = (u >> 2) & 31;
        const int r  = u >> 7;
        const int h  = h0 - 1 + r;
        bf16x8 v = {0, 0, 0, 0, 0, 0, 0, 0};
        if (h >= 0 && h < 32)
            v = *(const bf16x8*)(ab + (size_t)(h * 32 + w) * CD + cg);
        *(bf16x8*)&xs[r][1 + w][cg] = v;
    }
    __syncthreads();

    const int wvid = tid >> 6;
    const int lane = tid & 63;
    const int ln   = lane & 31;
    const int lh   = lane >> 5;
    const int nt0  = wvid * 2;

    f32x16 acc[2][2];
#pragma unroll
    for (int m = 0; m < 2; ++m)
#pragma unroll
        for (int n = 0; n < 2; ++n)
#pragma unroll
            for (int i = 0; i < 16; ++i) acc[m][n][i] = 0.f;

    const ushort_t* wl2 = wt2 + lane * 8;

#pragma unroll 1
    for (int tap = 0; tap < 9; ++tap) {
        const int dh = tap / 3;
        const int dw = tap % 3;
        const int wofs = tap * 2048;
#pragma unroll
        for (int kc = 0; kc < 2; ++kc) {
            const int c0 = kc * 16 + lh * 8;
            const bf16x8 a0 = *(const bf16x8*)(wl2 + wofs + kc * 512);
            const bf16x8 a1 = *(const bf16x8*)(wl2 + wofs + kc * 512 + 1024);
            const bf16x8 b0 = *(const bf16x8*)&xs[nt0 + dh    ][ln + dw][c0];
            const bf16x8 b1 = *(const bf16x8*)&xs[nt0 + 1 + dh][ln + dw][c0];
            acc[0][0] = __builtin_amdgcn_mfma_f32_32x32x16_bf16(a0, b0, acc[0][0], 0, 0, 0);
            acc[0][1] = __builtin_amdgcn_mfma_f32_32x32x16_bf16(a0, b1, acc[0][1], 0, 0, 0);
            acc[1][0] = __builtin_amdgcn_mfma_f32_32x32x16_bf16(a1, b0, acc[1][0], 0, 0, 0);
            acc[1][1] = __builtin_amdgcn_mfma_f32_32x32x16_bf16(a1, b1, acc[1][1], 0, 0, 0);
        }
    }

#pragma unroll
    for (int mt = 0; mt < 2; ++mt) {
        float* dst = out + (((size_t)b * CC + mt * 32) * SS + s) * HWHW;
#pragma unroll
        for (int ntl = 0; ntl < 2; ++ntl) {
            const int gp = (h0 + nt0 + ntl) * 32 + ln;
#pragma unroll
            for (int r = 0; r < 16; ++r) {
                const int m = (r & 3) + 8 * (r >> 2) + 4 * lh;
                dst[(size_t)m * SS * HWHW + gp] = acc[mt][ntl][r] + bo[mt * 32 + m];
            }
        }
    }
}

extern "C" void kernel_launch(void* const* d_in, const int* in_sizes, int n_in,
                              void* d_out, int out_size, void* d_ws, size_t ws_size,
                              hipStream_t stream)
{
    const float* x  = (const float*)d_in[0];
    const float* wq = (const float*)d_in[1];
    const float* bq = (const float*)d_in[2];
    const float* wk = (const float*)d_in[3];
    const float* bk = (const float*)d_in[4];
    const float* wv = (const float*)d_in[5];
    const float* bv = (const float*)d_in[6];
    const float* wo = (const float*)d_in[7];
    const float* bo = (const float*)d_in[8];
    float* out = (float*)d_out;

    ushort_t* qkv = (ushort_t*)d_ws;                                   // 192 MiB
    ushort_t* wt  = (ushort_t*)((char*)d_ws + (size_t)3 * QELEMS * 2); // 108 KiB
    ushort_t* wt2 = wt + 9 * 96 * 64;                                  // 36 KiB
    // xT (128 MiB bf16) lives in the out buffer (256 MiB fp32), dead until conv_out.
    ushort_t* xT   = (ushort_t*)d_out;
    // attT reuses the k region (exactly QELEMS elems), dead after attn.
    ushort_t* attT = qkv + (size_t)QELEMS;

    transpose_x<<<dim3(BB * SS), 256, 0, stream>>>(x, xT);
    pack_weights<<<288, 256, 0, stream>>>(wq, wk, wv, wo, wt, wt2);
    conv_qkv_mfma<<<dim3(BB * SS * 4), 256, 0, stream>>>(xT, wt, bq, bk, bv, qkv);
    attn_kernel<<<dim3(BB * CD), 256, 0, stream>>>(qkv);
    transpose_att<<<dim3(BB * SS), 256, 0, stream>>>(qkv, attT);
    conv_out_mfma<<<dim3(BB * SS * 4), 256, 0, stream>>>(attT, wt2, bo, out);
}